// Round 4
// baseline (190.377 us; speedup 1.0000x reference)
//
#include <hip/hip_runtime.h>
#include <hip/hip_bf16.h>

#define NROWS 16384
#define DDIM  256
#define LOG2E 1.44269504088896f

typedef __attribute__((ext_vector_type(8))) short bh8;    // 8 x bf16 (4 VGPR)
typedef __attribute__((ext_vector_type(4))) short bh4;
typedef __attribute__((ext_vector_type(4))) float fx4;
typedef __attribute__((ext_vector_type(16))) float fx16;  // 32x32 accumulator

__device__ __forceinline__ short f2bf(float x) {
  __hip_bfloat16 h = __float2bfloat16(x);
  return *reinterpret_cast<short*>(&h);
}

__device__ __forceinline__ float fexp2(float x) {
#if __has_builtin(__builtin_amdgcn_exp2f)
  return __builtin_amdgcn_exp2f(x);   // v_exp_f32: D = 2^S0
#else
  return __expf(x * 0.6931471805599453f);
#endif
}

__device__ __forceinline__ fx16 fzero16() {
  fx16 z;
#pragma unroll
  for (int q = 0; q < 16; ++q) z[q] = 0.f;
  return z;
}

template <int N>
__device__ __forceinline__ void vmw() {
  asm volatile("s_waitcnt vmcnt(%0)" ::"i"(N) : "memory");
}

// exact softplus, used only on the 16384 diagonal elements
__device__ __forceinline__ float softplus_f(float y) {
  float a = fabsf(y);
  float t = __expf(-a);
  float l;
  if (t < 0.125f) {
    l = t * (1.0f - t * (0.5f - 0.333333333f * t));
  } else {
    l = log1pf(t);
  }
  return fmaxf(y, 0.0f) + l;
}

__global__ void cast_bf16_kernel(const float* __restrict__ in,
                                 unsigned short* __restrict__ out) {
  int i = (blockIdx.x * blockDim.x + threadIdx.x) * 8;
  float4 v0 = *(const float4*)(in + i);
  float4 v1 = *(const float4*)(in + i + 4);
  bh8 o;
  o[0] = f2bf(v0.x); o[1] = f2bf(v0.y); o[2] = f2bf(v0.z); o[3] = f2bf(v0.w);
  o[4] = f2bf(v1.x); o[5] = f2bf(v1.y); o[6] = f2bf(v1.z); o[7] = f2bf(v1.w);
  *(bh8*)((unsigned short*)out + i) = o;
}

// ================= persistent strip kernel (fragment-resident LDS) =========
// 256 blocks (1/CU), 512 threads = 8 waves (2 wr x 4 wc), wave tile 64x128
// via 2x4 tiles of mfma_f32_32x32x16_bf16 (acc 8 x fx16 = 128 VGPR).
// Block owns 128 img rows (rp) and 8192 txt rows (cg). B processed as 16
// tiles of 512 cols, each in 8 K=32 chunks -> 128 chunk-steps.
// LDS: A panel 64KB @0 = 64 frags (r0..3 x s0..15) of 1KB, frag-resident:
//   frag holds row=r*32+(l&31), k=s*16+(l>>5)*8 at offset frag*1024+l*16.
// B ring: NB x 32KB, each chunk = 32 frags (c0..15 x s0..1), same scheme.
// Every ds_read_b128 is wave-linear (lane*16) -> zero bank conflicts.

// stage B chunk t into buffer bufp (4 global_load_lds per thread)
#define STB(t, bufp)                                                           \
  do {                                                                         \
    const int bt_ = (t) >> 3, kq_ = (t) & 7;                                   \
    const unsigned short* Bb_ =                                                \
        Bm + (size_t)(colgbase + bt_ * 512) * DDIM + kq_ * 32;                 \
    _Pragma("unroll")                                                          \
    for (int it_ = 0; it_ < 4; ++it_) {                                        \
      int fb_ = it_ * 8 + wave; /* 0..31 */                                    \
      int cc_ = fb_ >> 1, ss_ = fb_ & 1;                                       \
      __builtin_amdgcn_global_load_lds(                                        \
          (const __attribute__((address_space(1))) void*)(                     \
              Bb_ + (size_t)(cc_ * 32 + (lane & 31)) * DDIM + ss_ * 16 +       \
              (lane >> 5) * 8),                                                \
          (__attribute__((address_space(3))) void*)((bufp) + it_ * 8192 +      \
                                                    wave * 1024),              \
          16, 0, 0);                                                           \
    }                                                                          \
  } while (0)

// one K=32 chunk-step: 12 linear ds_read_b128 + 16 MFMA(32x32x16) per wave
#define COMPUTE(kq, bufp)                                                      \
  do {                                                                         \
    const char* aw_ = ldsA + wr * 32768 + (kq) * 2048 + lane * 16;             \
    const char* bw_ = (bufp) + wc * 8192 + lane * 16;                          \
    _Pragma("unroll")                                                          \
    for (int s_ = 0; s_ < 2; ++s_) {                                           \
      bh8 a0_ = *(const bh8*)(aw_ + s_ * 1024);                                \
      bh8 a1_ = *(const bh8*)(aw_ + 16384 + s_ * 1024);                        \
      bh8 b0_ = *(const bh8*)(bw_ + s_ * 1024);                                \
      bh8 b1_ = *(const bh8*)(bw_ + 2048 + s_ * 1024);                         \
      bh8 b2_ = *(const bh8*)(bw_ + 4096 + s_ * 1024);                         \
      bh8 b3_ = *(const bh8*)(bw_ + 6144 + s_ * 1024);                         \
      __builtin_amdgcn_s_setprio(1);                                           \
      acc00 = __builtin_amdgcn_mfma_f32_32x32x16_bf16(a0_, b0_, acc00, 0,0,0); \
      acc01 = __builtin_amdgcn_mfma_f32_32x32x16_bf16(a0_, b1_, acc01, 0,0,0); \
      acc02 = __builtin_amdgcn_mfma_f32_32x32x16_bf16(a0_, b2_, acc02, 0,0,0); \
      acc03 = __builtin_amdgcn_mfma_f32_32x32x16_bf16(a0_, b3_, acc03, 0,0,0); \
      acc10 = __builtin_amdgcn_mfma_f32_32x32x16_bf16(a1_, b0_, acc10, 0,0,0); \
      acc11 = __builtin_amdgcn_mfma_f32_32x32x16_bf16(a1_, b1_, acc11, 0,0,0); \
      acc12 = __builtin_amdgcn_mfma_f32_32x32x16_bf16(a1_, b2_, acc12, 0,0,0); \
      acc13 = __builtin_amdgcn_mfma_f32_32x32x16_bf16(a1_, b3_, acc13, 0,0,0); \
      __builtin_amdgcn_s_setprio(0);                                           \
    }                                                                          \
  } while (0)

// per-tile epilogue for one 32x32 acc; C layout (m74/m101):
// col = lane&31, row = (reg&3) + 8*(reg>>2) + 4*(lane>>5)
#define EPI(A_, m_, n_)                                                        \
  do {                                                                         \
    fx16 v_ = A_;                                                              \
    A_ = fzero16();                                                            \
    _Pragma("unroll")                                                          \
    for (int g_ = 0; g_ < 16; g_ += 4) {                                       \
      e0 += fexp2(k1 * v_[g_ + 0]);                                            \
      e1 += fexp2(k1 * v_[g_ + 1]);                                            \
      e2 += fexp2(k1 * v_[g_ + 2]);                                            \
      e3 += fexp2(k1 * v_[g_ + 3]);                                            \
    }                                                                          \
    if (dtile) { /* block-uniform: 1 of 16 tiles */                            \
      const int gcol_ = colbase + wc * 128 + (n_) * 32 + (lane & 31);          \
      const int grow0_ = rowbase + wr * 64 + (m_) * 32 + 4 * (lane >> 5);      \
      _Pragma("unroll")                                                        \
      for (int reg_ = 0; reg_ < 16; ++reg_) {                                  \
        int grow_ = grow0_ + (reg_ & 3) + 8 * (reg_ >> 2);                     \
        if (grow_ == gcol_) {                                                  \
          d += softplus_f(-fmaf(scale, v_[reg_], bias));                       \
          e0 -= fexp2(k1 * v_[reg_]);                                          \
        }                                                                      \
      }                                                                        \
    }                                                                          \
  } while (0)

#define EPILOGUE(btv)                                                          \
  do {                                                                         \
    const int colbase = colgbase + (btv) * 512;                                \
    const bool dtile = (colbase < rowbase + 128) && (rowbase < colbase + 512); \
    EPI(acc00, 0, 0); EPI(acc01, 0, 1); EPI(acc02, 0, 2); EPI(acc03, 0, 3);    \
    EPI(acc10, 1, 0); EPI(acc11, 1, 1); EPI(acc12, 1, 2); EPI(acc13, 1, 3);    \
  } while (0)

template <int NB>
__global__ __launch_bounds__(512, 2) void siglip_strip(
    const unsigned short* __restrict__ Am, const unsigned short* __restrict__ Bm,
    const float* __restrict__ scale_p, const float* __restrict__ bias_p,
    float* __restrict__ out) {
  extern __shared__ char smem[];
  char* ldsA = smem;  // 64KB
  char* b0 = smem + 65536;
  char* b1 = smem + 65536 + 32768;
  char* b2 = (NB == 3) ? (smem + 65536 + 65536) : b0;  // unused if NB==2

  const int tid  = threadIdx.x;
  const int lane = tid & 63;
  const int wave = tid >> 6;
  const int wr   = wave >> 2;  // 0..1
  const int wc   = wave & 3;   // 0..3
  const int rp   = blockIdx.x >> 1;
  const int cg   = blockIdx.x & 1;
  const int rowbase  = rp * 128;
  const int colgbase = cg * 8192;

  float scale = *scale_p;
  float bias  = *bias_p;
  asm volatile("" : "+v"(scale), "+v"(bias));
  const float k1 = scale * LOG2E;
  const float p0 = fexp2(bias * LOG2E);  // e^bias
  // drain any vmem the scalar loads may have issued, so counted vmcnt below
  // sees only staging loads
  asm volatile("s_waitcnt vmcnt(0)" ::: "memory");

  // ---- prologue: A panel (64 frags) + first NB B chunks ----
  {
    const unsigned short* Ab = Am + (size_t)rowbase * DDIM;
#pragma unroll
    for (int it = 0; it < 8; ++it) {
      int fa = it * 8 + wave;  // 0..63
      int r = fa >> 4, s = fa & 15;
      __builtin_amdgcn_global_load_lds(
          (const __attribute__((address_space(1))) void*)(
              Ab + (size_t)(r * 32 + (lane & 31)) * DDIM + s * 16 +
              (lane >> 5) * 8),
          (__attribute__((address_space(3))) void*)(ldsA + it * 8192 +
                                                    wave * 1024),
          16, 0, 0);
    }
  }
  STB(0, b0);
  STB(1, b1);
  if (NB == 3) STB(2, b2);

  fx16 acc00 = fzero16(), acc01 = fzero16(), acc02 = fzero16(),
       acc03 = fzero16();
  fx16 acc10 = fzero16(), acc11 = fzero16(), acc12 = fzero16(),
       acc13 = fzero16();
  float e0 = 0.f, e1 = 0.f, e2 = 0.f, e3 = 0.f, d = 0.f;

  constexpr int WAITN = 4 * (NB - 1);
  vmw<WAITN>();  // A + chunk0 landed (in-order completion)

  for (int bt = 0; bt < 15; ++bt) {
    const int tb = bt * 8;
#pragma unroll
    for (int kq = 0; kq < 8; ++kq) {
      vmw<WAITN>();
      __builtin_amdgcn_s_barrier();
      COMPUTE(kq, b0);
      __builtin_amdgcn_s_barrier();
      STB(tb + kq + NB, b0);  // refill just-consumed buffer
      char* t_ = b0;
      b0 = b1;
      if (NB == 3) { b1 = b2; b2 = t_; } else { b1 = t_; }
    }
    EPILOGUE(bt);  // overlaps with the 2 in-flight chunks' DMA
  }

  // ---- peeled bt = 15 (tail waits, no overflow stages) ----
  {
    const int tb = 120;
#pragma unroll
    for (int kq = 0; kq < 8; ++kq) {
      if (kq <= 5) vmw<WAITN>();
      else if (kq == 6) vmw<4>();
      else vmw<0>();
      __builtin_amdgcn_s_barrier();
      COMPUTE(kq, b0);
      __builtin_amdgcn_s_barrier();
      if (tb + kq + NB < 128) STB(tb + kq + NB, b0);
      char* t_ = b0;
      b0 = b1;
      if (NB == 3) { b1 = b2; b2 = t_; } else { b1 = t_; }
    }
    EPILOGUE(15);
  }

  float local = fmaf((e0 + e1) + (e2 + e3), p0, d);
#pragma unroll
  for (int off = 32; off > 0; off >>= 1) local += __shfl_xor(local, off, 64);
  if (lane == 0) atomicAdd(out, local * (1.0f / 16384.0f));
}

// ===================== fallback: f32 inputs, reg-staged (no ws needed) =====
__device__ __forceinline__ unsigned swz256(unsigned o) {
  return o ^ (((o >> 8) & 7u) << 4);
}

__device__ __forceinline__ void map_tile(int bid, int& tr, int& tc) {
  int xcd = bid & 7;
  int idx = bid >> 3;
  int g   = idx >> 7;
  int w   = idx & 127;
  tr = xcd * 16 + (w >> 3);
  tc = g * 8 + (w & 7);
}

__global__ __launch_bounds__(256, 2) void siglip_fallback(
    const float* __restrict__ A, const float* __restrict__ B,
    const float* __restrict__ scale_p, const float* __restrict__ bias_p,
    float* __restrict__ out) {
  __shared__ char lds[65536];
  char* ldsA = lds;
  char* ldsB = lds + 32768;
  const int tid  = threadIdx.x;
  const int lane = tid & 63;
  const int wave = tid >> 6;
  const int wr   = wave >> 1;
  const int wc   = wave & 1;
  int tr, tc;
  map_tile(blockIdx.x, tr, tc);
  const int brow = tr * 128, bcol = tc * 128;

  fx4 acc[4][4];
#pragma unroll
  for (int m = 0; m < 4; ++m)
#pragma unroll
    for (int n = 0; n < 4; ++n) acc[m][n] = (fx4){0.f, 0.f, 0.f, 0.f};

#pragma unroll
  for (int p = 0; p < 2; ++p) {
    __syncthreads();
    const float* Af = A + (size_t)brow * DDIM + p * 128;
    const float* Bf = B + (size_t)bcol * DDIM + p * 128;
#pragma unroll
    for (int it = 0; it < 16; ++it) {
      int c = it * 256 + tid;
      int row = c >> 5, j = c & 31;
      unsigned o = row * 256 + j * 8;
      {
        float4 v = *(const float4*)(Af + (size_t)row * DDIM + j * 4);
        bh4 h;
        h[0] = f2bf(v.x); h[1] = f2bf(v.y); h[2] = f2bf(v.z); h[3] = f2bf(v.w);
        *(bh4*)(ldsA + swz256(o)) = h;
      }
      {
        float4 v = *(const float4*)(Bf + (size_t)row * DDIM + j * 4);
        bh4 h;
        h[0] = f2bf(v.x); h[1] = f2bf(v.y); h[2] = f2bf(v.z); h[3] = f2bf(v.w);
        *(bh4*)(ldsB + swz256(o)) = h;
      }
    }
    __syncthreads();
#pragma unroll
    for (int kk = 0; kk < 4; ++kk) {
      const int colb = kk * 64 + (lane >> 4) * 16;
      bh8 a[4], b[4];
#pragma unroll
      for (int m = 0; m < 4; ++m) {
        int r = wr * 64 + m * 16 + (lane & 15);
        a[m] = *(const bh8*)(ldsA + swz256((unsigned)(r * 256 + colb)));
      }
#pragma unroll
      for (int n = 0; n < 4; ++n) {
        int r = wc * 64 + n * 16 + (lane & 15);
        b[n] = *(const bh8*)(ldsB + swz256((unsigned)(r * 256 + colb)));
      }
#pragma unroll
      for (int m = 0; m < 4; ++m)
#pragma unroll
        for (int n = 0; n < 4; ++n)
          acc[m][n] = __builtin_amdgcn_mfma_f32_16x16x32_bf16(a[m], b[n],
                                                              acc[m][n], 0, 0, 0);
    }
  }

  const float scale = *scale_p;
  const float bias  = *bias_p;
  const float k1 = scale * LOG2E;
  const float k0 = bias * LOG2E;
  float s0 = 0.f, s1 = 0.f, s2 = 0.f, s3 = 0.f;
  const int  row0 = brow + wr * 64 + (lane >> 4) * 4;
  const int  col0 = bcol + wc * 64 + (lane & 15);
  const bool isdiag = (tr == tc);
#pragma unroll
  for (int m = 0; m < 4; ++m) {
#pragma unroll
    for (int n = 0; n < 4; ++n) {
      fx4 v = acc[m][n];
      s0 += fexp2(fmaf(k1, v[0], k0));
      s1 += fexp2(fmaf(k1, v[1], k0));
      s2 += fexp2(fmaf(k1, v[2], k0));
      s3 += fexp2(fmaf(k1, v[3], k0));
      if (isdiag) {
        const int gj = col0 + n * 16;
#pragma unroll
        for (int j = 0; j < 4; ++j) {
          const int gi = row0 + m * 16 + j;
          if (gi == gj) {
            float logit = fmaf(scale, v[j], bias);
            s0 += softplus_f(-logit) - fexp2(fmaf(k1, v[j], k0));
          }
        }
      }
    }
  }
  float local = (s0 + s1) + (s2 + s3);
#pragma unroll
  for (int off = 32; off > 0; off >>= 1) local += __shfl_xor(local, off, 64);

  __syncthreads();
  float* red = (float*)lds;
  if (lane == 0) red[wave] = local;
  __syncthreads();
  if (tid == 0)
    atomicAdd(out, (red[0] + red[1] + red[2] + red[3]) * (1.0f / 16384.0f));
}

extern "C" void kernel_launch(void* const* d_in, const int* in_sizes, int n_in,
                              void* d_out, int out_size, void* d_ws,
                              size_t ws_size, hipStream_t stream) {
  const float* img     = (const float*)d_in[0];
  const float* txt     = (const float*)d_in[1];
  const float* scale_p = (const float*)d_in[2];
  const float* bias_p  = (const float*)d_in[3];
  float* out = (float*)d_out;

  hipMemsetAsync(d_out, 0, (size_t)out_size * sizeof(float), stream);

  const size_t elems = (size_t)NROWS * DDIM;
  const size_t need  = 2 * elems * sizeof(unsigned short);  // 16.8 MB

  if (ws_size >= need) {
    unsigned short* Abf = (unsigned short*)d_ws;
    unsigned short* Bbf = Abf + elems;
    const int cast_blocks = (int)(elems / (256 * 8));  // 2048
    cast_bf16_kernel<<<cast_blocks, 256, 0, stream>>>(img, Abf);
    cast_bf16_kernel<<<cast_blocks, 256, 0, stream>>>(txt, Bbf);

    hipError_t a3 = hipFuncSetAttribute(
        (const void*)siglip_strip<3>,
        hipFuncAttributeMaxDynamicSharedMemorySize, 163840);
    if (a3 == hipSuccess) {
      siglip_strip<3><<<256, 512, 163840, stream>>>(Abf, Bbf, scale_p, bias_p,
                                                    out);
      return;
    }
    hipError_t a2 = hipFuncSetAttribute(
        (const void*)siglip_strip<2>,
        hipFuncAttributeMaxDynamicSharedMemorySize, 131072);
    if (a2 == hipSuccess) {
      siglip_strip<2><<<256, 512, 131072, stream>>>(Abf, Bbf, scale_p, bias_p,
                                                    out);
      return;
    }
  }
  const int nblocks = (NROWS / 128) * (NROWS / 128);  // 16384
  siglip_fallback<<<nblocks, 256, 0, stream>>>(img, txt, scale_p, bias_p, out);
}